// Round 8
// baseline (273.428 us; speedup 1.0000x reference)
//
#include <hip/hip_runtime.h>
#include <hip/hip_fp16.h>
#include <stdint.h>

#define O_FEAT 4096
#define I_FEAT 4096
#define M_DIM  2048
#define K_DIM  4096

typedef __attribute__((ext_vector_type(8))) short short8;   // 8 x bf16 (4 VGPRs)
typedef __attribute__((ext_vector_type(2))) short short2v;  // 2 x bf16 (1 VGPR)
typedef __attribute__((ext_vector_type(4))) float floatx4;  // MFMA accumulator

#define AS1 __attribute__((address_space(1)))
#define AS3 __attribute__((address_space(3)))

__device__ __forceinline__ uint16_t f32_to_bf16(float f) {
    uint32_t u = __builtin_bit_cast(uint32_t, f);
    u = (u + 0x7FFFu + ((u >> 16) & 1u)) >> 16;   // round-to-nearest-even
    return (uint16_t)u;
}
__device__ __forceinline__ float bf16_to_f32(uint16_t h) {
    uint32_t u = ((uint32_t)h) << 16;
    return __builtin_bit_cast(float, u);
}

// async global->LDS, 16B per lane; LDS dest = wave-uniform base + lane*16
__device__ __forceinline__ void load_lds16(const uint16_t* gptr, uint16_t* ldsptr) {
    __builtin_amdgcn_global_load_lds((const AS1 uint32_t*)gptr,
                                     (AS3 uint32_t*)ldsptr, 16, 0, 0);
}

// ---------------------------------------------------------------------------
// Kernel 1: dequant int4 -> bf16 W.  (R1-exact)
// ---------------------------------------------------------------------------
__global__ __launch_bounds__(256) void dequant_kernel(
        const void*  __restrict__ packed,
        const float* __restrict__ scales,
        uint16_t*    __restrict__ W) {
    const int lane = threadIdx.x & 63;
    uint32_t probe = ((const uint32_t*)packed)[lane];
    const bool int32mode = (__ballot(probe >= 256u) == 0ull);

    int idx = blockIdx.x * 256 + threadIdx.x;       // 2,097,152 threads
    float s = scales[idx >> 9];                     // 512 byte-quads per row

    uint32_t bytes4;
    if (int32mode) {
        uint4 w = ((const uint4*)packed)[idx];      // 4 int32, each 0..255
        bytes4 = (w.x & 0xFFu) | ((w.y & 0xFFu) << 8) |
                 ((w.z & 0xFFu) << 16) | ((w.w & 0xFFu) << 24);
    } else {
        bytes4 = ((const uint32_t*)packed)[idx];
    }

    uint16_t o[8];
#pragma unroll
    for (int b = 0; b < 4; ++b) {
        int byte = (bytes4 >> (8 * b)) & 0xFF;
        o[2 * b]     = f32_to_bf16((float)((byte & 0xF) - 8) * s);  // low -> even
        o[2 * b + 1] = f32_to_bf16((float)((byte >> 4) - 8) * s);   // high -> odd
    }
    uint4 v;
    v.x = (uint32_t)o[0] | ((uint32_t)o[1] << 16);
    v.y = (uint32_t)o[2] | ((uint32_t)o[3] << 16);
    v.z = (uint32_t)o[4] | ((uint32_t)o[5] << 16);
    v.w = (uint32_t)o[6] | ((uint32_t)o[7] << 16);
    ((uint4*)W)[idx] = v;
}

// ---------------------------------------------------------------------------
// Kernel 2 (fused): [0,3328) scatter COO residual into W; [3328,7424)
// x -> bf16 Xb; [7424,15616) zero C (split-K GEMM atomically accumulates).
// ---------------------------------------------------------------------------
#define SCATTER_BLOCKS 3328
#define XCONV_END      7424
#define K2_BLOCKS      15616
__global__ __launch_bounds__(256) void scatter_xconv_zero_kernel(
        const void*  __restrict__ vals,
        const int*   __restrict__ rows,
        const int*   __restrict__ cols,
        const float* __restrict__ alpha,
        const float* __restrict__ x,
        uint16_t*    __restrict__ W,
        uint16_t*    __restrict__ Xb,
        float*       __restrict__ C,
        int nnz) {
    if (blockIdx.x < SCATTER_BLOCKS) {
        const int lane = threadIdx.x & 63;
        float p = fabsf(((const float*)vals)[lane]);
        int cnt = __popcll(__ballot(p > 1e-4f && p < 1.0f));
        const bool f32mode = (cnt >= 32);

        int i = blockIdx.x * 256 + threadIdx.x;
        if (i >= nnz) return;
        float v = f32mode ? ((const float*)vals)[i]
                          : __half2float(((const __half*)vals)[i]);
        v *= alpha[0];
        int r = rows[i], c = cols[i];
        size_t elem = (size_t)r * I_FEAT + c;

#if __has_builtin(__builtin_amdgcn_global_atomic_fadd_v2bf16)
        const bool hi = (elem & 1);
        short b = (short)f32_to_bf16(v);
        short2v val;
        val[0] = hi ? (short)0 : b;
        val[1] = hi ? b : (short)0;
        __builtin_amdgcn_global_atomic_fadd_v2bf16(
            (AS1 short2v*)(W + (elem & ~(size_t)1)), val);
#else
        uint32_t* word = (uint32_t*)W + (elem >> 1);
        bool hi = (c & 1);
        uint32_t old = *word, assumed;
        do {
            assumed = old;
            uint16_t cur = hi ? (uint16_t)(assumed >> 16) : (uint16_t)(assumed & 0xFFFF);
            uint16_t nw  = f32_to_bf16(bf16_to_f32(cur) + v);
            uint32_t neww = hi ? ((assumed & 0x0000FFFFu) | ((uint32_t)nw << 16))
                               : ((assumed & 0xFFFF0000u) | (uint32_t)nw);
            old = atomicCAS(word, assumed, neww);
        } while (old != assumed);
#endif
    } else if (blockIdx.x < XCONV_END) {
        int idx = (blockIdx.x - SCATTER_BLOCKS) * 256 + threadIdx.x;  // 1,048,576
        float4 v0 = ((const float4*)x)[2 * idx];
        float4 v1 = ((const float4*)x)[2 * idx + 1];
        uint4 o;
        o.x = (uint32_t)f32_to_bf16(v0.x) | ((uint32_t)f32_to_bf16(v0.y) << 16);
        o.y = (uint32_t)f32_to_bf16(v0.z) | ((uint32_t)f32_to_bf16(v0.w) << 16);
        o.z = (uint32_t)f32_to_bf16(v1.x) | ((uint32_t)f32_to_bf16(v1.y) << 16);
        o.w = (uint32_t)f32_to_bf16(v1.z) | ((uint32_t)f32_to_bf16(v1.w) << 16);
        ((uint4*)Xb)[idx] = o;
    } else {
        // zero C: 8192 blocks x 256 thr x 16B = 32 MB exact
        int zidx = (blockIdx.x - XCONV_END) * 256 + threadIdx.x;
        ((uint4*)C)[zidx] = uint4{0u, 0u, 0u, 0u};
    }
}

// ---------------------------------------------------------------------------
// Kernel 3: C[M,N] += A[M,K] * B[N,K]^T  (bf16 in, fp32 atomic-accum out).
// R15: R14 (256^2 + split-K=2, 4 phases x 16 MFMA) with ONE change: all 8
// stage chunks of tile t+1 issue at P1 instead of 3/3/2 across P1-P3.
// R14's 8376 cyc/tile had a ~3000-cyc residual = tile-end vmcnt(0) waiting
// on loads only ~1 phase (~600 cyc) old — younger than L2-miss latency
// (~900), all 8 waves blocked, no sibling block (m218: drain-on-young-loads
// voids the pipeline).  sb is free for the whole tile (held t-1, fully
// consumed before the tile-t entry barrier — R14 invariant), so all 8 can
// issue at P1 -> drained loads are ~3.5 phases (>2000 cyc) old ==
// functionally m201's counted-vmcnt (load AGE at wait is the mechanism).
// Everything else bit-identical to passing R14.
// ---------------------------------------------------------------------------
#define BK 64
#define NT_BLK 32                        // 2048 K per block / 64
#define DBUF 32768                       // elems per buffer (A 16384 + B 16384)

#define MF(i, j, A_, B_) acc[i][j] = __builtin_amdgcn_mfma_f32_16x16x32_bf16(A_, B_, acc[i][j], 0, 0, 0)
#define ROW4(i, A_, B0_, B1_, B2_, B3_) \
    MF(i, 0, A_, B0_); MF(i, 1, A_, B1_); MF(i, 2, A_, B2_); MF(i, 3, A_, B3_)

__global__ __launch_bounds__(512, 2) void gemm_bt_kernel(
        const uint16_t* __restrict__ A,   // [2048][4096] bf16
        const uint16_t* __restrict__ B,   // [4096][4096] bf16 (row-major [N][K])
        float* __restrict__ C) {          // [2048][4096] fp32 (pre-zeroed)
    __shared__ uint16_t lds[2 * DBUF];    // 128 KiB

    const int tid  = threadIdx.x;
    const int wave = tid >> 6;            // 0..7
    const int lane = tid & 63;
    const int wm   = wave >> 2;           // 0..1: A-row half (128 rows)
    const int wn   = wave & 3;            // 0..3: B-col quarter (64 cols)

    // XCD swizzle (bijective, 256%8==0); consecutive swz = same output tile's
    // two K-halves -> same XCD L2 for C atomics + A/B panels.
    const int wgid = blockIdx.x;
    const int swz  = (wgid & 7) * 32 + (wgid >> 3);
    const int tile = swz >> 1;            // 0..127
    const int ks   = swz & 1;             // K-half
    const int bm0  = (tile >> 4) * 256;   // 8 row-tiles
    const int bn0  = (tile & 15) * 256;   // 16 col-tiles
    const int kb   = ks * 2048;

    // ---- staging (R9 involution): LDS[r][q] <- global[r][q^(r&7)] ----
    const int srow = wave * 8 + (lane >> 3);             // 0..63 per chunk
    const int xcol = ((lane & 7) ^ (lane >> 3)) << 3;
    const uint16_t* gA = A + (size_t)(bm0 + srow) * K_DIM + kb + xcol;
    const uint16_t* gB = B + (size_t)(bn0 + srow) * K_DIM + kb + xcol;
    const int ldsw = wave * 512;          // per-call wave slot inside 4096-chunk

    // ---- fragment addressing (R9-exact; row&7 == fr&7) ----
    const int fr  = lane & 15;
    const int ko  = (lane >> 4) << 3;
    const int sk0 = (ko)      ^ ((fr & 7) << 3);
    const int sk1 = (32 + ko) ^ ((fr & 7) << 3);
    const int ao0 = (wm * 128 +   0 + fr) * 64;
    const int ao1 = (wm * 128 +  16 + fr) * 64;
    const int ao2 = (wm * 128 +  32 + fr) * 64;
    const int ao3 = (wm * 128 +  48 + fr) * 64;
    const int ao4 = (wm * 128 +  64 + fr) * 64;
    const int ao5 = (wm * 128 +  80 + fr) * 64;
    const int ao6 = (wm * 128 +  96 + fr) * 64;
    const int ao7 = (wm * 128 + 112 + fr) * 64;
    const int bo0 = 16384 + (wn * 64 +  0 + fr) * 64;
    const int bo1 = 16384 + (wn * 64 + 16 + fr) * 64;
    const int bo2 = 16384 + (wn * 64 + 32 + fr) * 64;
    const int bo3 = 16384 + (wn * 64 + 48 + fr) * 64;

    floatx4 acc[8][4];
#pragma unroll
    for (int i = 0; i < 8; ++i)
#pragma unroll
        for (int j = 0; j < 4; ++j) acc[i][j] = {0.f, 0.f, 0.f, 0.f};

    // ---- prologue: stage tile 0 -> dbuf0 (A c0-3, B c0-3), drain ----
#pragma unroll
    for (int c = 0; c < 4; ++c)
        load_lds16(gA + (size_t)(c * 64) * K_DIM, &lds[c * 4096 + ldsw]);
#pragma unroll
    for (int c = 0; c < 4; ++c)
        load_lds16(gB + (size_t)(c * 64) * K_DIM, &lds[16384 + c * 4096 + ldsw]);
    asm volatile("s_waitcnt vmcnt(0)" ::: "memory");
    __builtin_amdgcn_s_barrier();

    for (int t = 0; t < NT_BLK; ++t) {
        const int  cb = (t & 1) << 15;            // compute buffer
        const int  sb = cb ^ DBUF;                // stage buffer (tile t+1)
        const bool pf = (t + 1 < NT_BLK);
        const int  kt = (t + 1) * BK;             // stage k offset

        // ---- P1: read A0-3 s0 + B0-3 s0 (8); stage ALL 8 chunks of t+1 ----
        short8 a0 = *(const short8*)&lds[cb + ao0 + sk0];
        short8 a1 = *(const short8*)&lds[cb + ao1 + sk0];
        short8 a2 = *(const short8*)&lds[cb + ao2 + sk0];
        short8 a3 = *(const short8*)&lds[cb + ao3 + sk0];
        short8 b0 = *(const short8*)&lds[cb + bo0 + sk0];
        short8 b1 = *(const short8*)&lds[cb + bo1 + sk0];
        short8 b2 = *(const short8*)&lds[cb + bo2 + sk0];
        short8 b3 = *(const short8*)&lds[cb + bo3 + sk0];
        if (pf) {
            load_lds16(gA + kt,                        &lds[sb + ldsw]);
            load_lds16(gA + kt + (size_t) 64 * K_DIM,  &lds[sb + 4096 + ldsw]);
            load_lds16(gA + kt + (size_t)128 * K_DIM,  &lds[sb + 8192 + ldsw]);
            load_lds16(gA + kt + (size_t)192 * K_DIM,  &lds[sb + 12288 + ldsw]);
            load_lds16(gB + kt,                        &lds[sb + 16384 + ldsw]);
            load_lds16(gB + kt + (size_t) 64 * K_DIM,  &lds[sb + 20480 + ldsw]);
            load_lds16(gB + kt + (size_t)128 * K_DIM,  &lds[sb + 24576 + ldsw]);
            load_lds16(gB + kt + (size_t)192 * K_DIM,  &lds[sb + 28672 + ldsw]);
        }
        __builtin_amdgcn_s_barrier();
        asm volatile("s_waitcnt lgkmcnt(0)");
        __builtin_amdgcn_s_setprio(1);
        ROW4(0, a0, b0, b1, b2, b3);
        ROW4(1, a1, b0, b1, b2, b3);
        ROW4(2, a2, b0, b1, b2, b3);
        ROW4(3, a3, b0, b1, b2, b3);
        __builtin_amdgcn_s_setprio(0);
        __builtin_amdgcn_s_barrier();

        // ---- P2: read A0-3 s1 + B0-3 s1 (8) ----
        short8 c0 = *(const short8*)&lds[cb + ao0 + sk1];
        short8 c1 = *(const short8*)&lds[cb + ao1 + sk1];
        short8 c2 = *(const short8*)&lds[cb + ao2 + sk1];
        short8 c3 = *(const short8*)&lds[cb + ao3 + sk1];
        short8 d0 = *(const short8*)&lds[cb + bo0 + sk1];
        short8 d1 = *(const short8*)&lds[cb + bo1 + sk1];
        short8 d2 = *(const short8*)&lds[cb + bo2 + sk1];
        short8 d3 = *(const short8*)&lds[cb + bo3 + sk1];
        __builtin_amdgcn_s_barrier();
        asm volatile("s_waitcnt lgkmcnt(0)");
        __builtin_amdgcn_s_setprio(1);
        ROW4(0, c0, d0, d1, d2, d3);
        ROW4(1, c1, d0, d1, d2, d3);
        ROW4(2, c2, d0, d1, d2, d3);
        ROW4(3, c3, d0, d1, d2, d3);
        __builtin_amdgcn_s_setprio(0);
        __builtin_amdgcn_s_barrier();

        // ---- P3: read A4-7 s0 (4)  (B s0 regs still live) ----
        short8 e0 = *(const short8*)&lds[cb + ao4 + sk0];
        short8 e1 = *(const short8*)&lds[cb + ao5 + sk0];
        short8 e2 = *(const short8*)&lds[cb + ao6 + sk0];
        short8 e3 = *(const short8*)&lds[cb + ao7 + sk0];
        __builtin_amdgcn_s_barrier();
        asm volatile("s_waitcnt lgkmcnt(0)");
        __builtin_amdgcn_s_setprio(1);
        ROW4(4, e0, b0, b1, b2, b3);
        ROW4(5, e1, b0, b1, b2, b3);
        ROW4(6, e2, b0, b1, b2, b3);
        ROW4(7, e3, b0, b1, b2, b3);
        __builtin_amdgcn_s_setprio(0);
        __builtin_amdgcn_s_barrier();

        // ---- P4: read A4-7 s1 (4); tile-end drain (loads ~3.5 phases old) --
        short8 f0 = *(const short8*)&lds[cb + ao4 + sk1];
        short8 f1 = *(const short8*)&lds[cb + ao5 + sk1];
        short8 f2 = *(const short8*)&lds[cb + ao6 + sk1];
        short8 f3 = *(const short8*)&lds[cb + ao7 + sk1];
        __builtin_amdgcn_s_barrier();
        asm volatile("s_waitcnt lgkmcnt(0)");
        __builtin_amdgcn_s_setprio(1);
        ROW4(4, f0, d0, d1, d2, d3);
        ROW4(5, f1, d0, d1, d2, d3);
        ROW4(6, f2, d0, d1, d2, d3);
        ROW4(7, f3, d0, d1, d2, d3);
        __builtin_amdgcn_s_setprio(0);
        if (pf) {
            asm volatile("s_waitcnt vmcnt(0)" ::: "memory");
            __builtin_amdgcn_s_barrier();
        }
    }

    // epilogue: C/D layout col=lane&15, row=(lane>>4)*4+reg [m89/m91];
    // fp32 atomic accumulate (split-K partner adds the other K-half).
    const int cn  = lane & 15;
    const int rb4 = (lane >> 4) * 4;
#pragma unroll
    for (int i = 0; i < 8; ++i)
#pragma unroll
        for (int j = 0; j < 4; ++j)
#pragma unroll
            for (int r = 0; r < 4; ++r) {
                const int row = bm0 + wm * 128 + i * 16 + rb4 + r;
                const int col = bn0 + wn * 64 + j * 16 + cn;
                atomicAdd(&C[(size_t)row * O_FEAT + col], acc[i][j][r]);
            }
}

// ---------------------------------------------------------------------------
extern "C" void kernel_launch(void* const* d_in, const int* in_sizes, int n_in,
                              void* d_out, int out_size, void* d_ws, size_t ws_size,
                              hipStream_t stream) {
    const float* x      = (const float*)d_in[0];
    const void*  packed = d_in[1];
    const float* scales = (const float*)d_in[2];
    const void*  vals   = d_in[3];
    const int*   rows   = (const int*)d_in[4];
    const int*   cols   = (const int*)d_in[5];
    const float* alpha  = (const float*)d_in[6];
    float*       out    = (float*)d_out;
    const int nnz = in_sizes[3];

    uint16_t* W  = (uint16_t*)d_ws;                                        // 32 MB
    uint16_t* Xb = (uint16_t*)((char*)d_ws + (size_t)O_FEAT * I_FEAT * 2); // 16 MB

    // 1) dequant int4 -> bf16 W
    dequant_kernel<<<8192, 256, 0, stream>>>(packed, scales, W);
    // 2) fused: scatter residual into W + x -> bf16 Xb + zero C
    scatter_xconv_zero_kernel<<<K2_BLOCKS, 256, 0, stream>>>(
        vals, rows, cols, alpha, x, W, Xb, out, nnz);
    // 3) GEMM split-K=2: out += Xb * W^T (256 blocks, 1/CU)
    gemm_bt_kernel<<<256, 512, 0, stream>>>(Xb, W, out);
}

// Round 9
// 226.270 us; speedup vs baseline: 1.2084x; 1.2084x over previous
//
#include <hip/hip_runtime.h>
#include <hip/hip_fp16.h>
#include <stdint.h>

#define O_FEAT 4096
#define I_FEAT 4096
#define M_DIM  2048
#define K_DIM  4096

typedef __attribute__((ext_vector_type(8))) short short8;   // 8 x bf16 (4 VGPRs)
typedef __attribute__((ext_vector_type(2))) short short2v;  // 2 x bf16 (1 VGPR)
typedef __attribute__((ext_vector_type(4))) float floatx4;  // MFMA accumulator

#define AS1 __attribute__((address_space(1)))
#define AS3 __attribute__((address_space(3)))

__device__ __forceinline__ uint16_t f32_to_bf16(float f) {
    uint32_t u = __builtin_bit_cast(uint32_t, f);
    u = (u + 0x7FFFu + ((u >> 16) & 1u)) >> 16;   // round-to-nearest-even
    return (uint16_t)u;
}
__device__ __forceinline__ float bf16_to_f32(uint16_t h) {
    uint32_t u = ((uint32_t)h) << 16;
    return __builtin_bit_cast(float, u);
}

// async global->LDS, 16B per lane; LDS dest = wave-uniform base + lane*16
__device__ __forceinline__ void load_lds16(const uint16_t* gptr, uint16_t* ldsptr) {
    __builtin_amdgcn_global_load_lds((const AS1 uint32_t*)gptr,
                                     (AS3 uint32_t*)ldsptr, 16, 0, 0);
}

// ---------------------------------------------------------------------------
// Kernel 1: dequant int4 -> bf16 W.  (R1-exact)
// ---------------------------------------------------------------------------
__global__ __launch_bounds__(256) void dequant_kernel(
        const void*  __restrict__ packed,
        const float* __restrict__ scales,
        uint16_t*    __restrict__ W) {
    const int lane = threadIdx.x & 63;
    uint32_t probe = ((const uint32_t*)packed)[lane];
    const bool int32mode = (__ballot(probe >= 256u) == 0ull);

    int idx = blockIdx.x * 256 + threadIdx.x;       // 2,097,152 threads
    float s = scales[idx >> 9];                     // 512 byte-quads per row

    uint32_t bytes4;
    if (int32mode) {
        uint4 w = ((const uint4*)packed)[idx];      // 4 int32, each 0..255
        bytes4 = (w.x & 0xFFu) | ((w.y & 0xFFu) << 8) |
                 ((w.z & 0xFFu) << 16) | ((w.w & 0xFFu) << 24);
    } else {
        bytes4 = ((const uint32_t*)packed)[idx];
    }

    uint16_t o[8];
#pragma unroll
    for (int b = 0; b < 4; ++b) {
        int byte = (bytes4 >> (8 * b)) & 0xFF;
        o[2 * b]     = f32_to_bf16((float)((byte & 0xF) - 8) * s);  // low -> even
        o[2 * b + 1] = f32_to_bf16((float)((byte >> 4) - 8) * s);   // high -> odd
    }
    uint4 v;
    v.x = (uint32_t)o[0] | ((uint32_t)o[1] << 16);
    v.y = (uint32_t)o[2] | ((uint32_t)o[3] << 16);
    v.z = (uint32_t)o[4] | ((uint32_t)o[5] << 16);
    v.w = (uint32_t)o[6] | ((uint32_t)o[7] << 16);
    ((uint4*)W)[idx] = v;
}

// ---------------------------------------------------------------------------
// Kernel 2 (fused): scatter COO residual into W (blocks < 3328) + x -> bf16
// (rest).  (R1-exact.)
// ---------------------------------------------------------------------------
#define SCATTER_BLOCKS 3328
__global__ __launch_bounds__(256) void scatter_xconv_kernel(
        const void*  __restrict__ vals,
        const int*   __restrict__ rows,
        const int*   __restrict__ cols,
        const float* __restrict__ alpha,
        const float* __restrict__ x,
        uint16_t*    __restrict__ W,
        uint16_t*    __restrict__ Xb,
        int nnz) {
    if (blockIdx.x < SCATTER_BLOCKS) {
        const int lane = threadIdx.x & 63;
        float p = fabsf(((const float*)vals)[lane]);
        int cnt = __popcll(__ballot(p > 1e-4f && p < 1.0f));
        const bool f32mode = (cnt >= 32);

        int i = blockIdx.x * 256 + threadIdx.x;
        if (i >= nnz) return;
        float v = f32mode ? ((const float*)vals)[i]
                          : __half2float(((const __half*)vals)[i]);
        v *= alpha[0];
        int r = rows[i], c = cols[i];
        size_t elem = (size_t)r * I_FEAT + c;

#if __has_builtin(__builtin_amdgcn_global_atomic_fadd_v2bf16)
        const bool hi = (elem & 1);
        short b = (short)f32_to_bf16(v);
        short2v val;
        val[0] = hi ? (short)0 : b;
        val[1] = hi ? b : (short)0;
        __builtin_amdgcn_global_atomic_fadd_v2bf16(
            (AS1 short2v*)(W + (elem & ~(size_t)1)), val);
#else
        uint32_t* word = (uint32_t*)W + (elem >> 1);
        bool hi = (c & 1);
        uint32_t old = *word, assumed;
        do {
            assumed = old;
            uint16_t cur = hi ? (uint16_t)(assumed >> 16) : (uint16_t)(assumed & 0xFFFF);
            uint16_t nw  = f32_to_bf16(bf16_to_f32(cur) + v);
            uint32_t neww = hi ? ((assumed & 0x0000FFFFu) | ((uint32_t)nw << 16))
                               : ((assumed & 0xFFFF0000u) | (uint32_t)nw);
            old = atomicCAS(word, assumed, neww);
        } while (old != assumed);
#endif
    } else {
        int idx = (blockIdx.x - SCATTER_BLOCKS) * 256 + threadIdx.x;  // 1,048,576
        float4 v0 = ((const float4*)x)[2 * idx];
        float4 v1 = ((const float4*)x)[2 * idx + 1];
        uint4 o;
        o.x = (uint32_t)f32_to_bf16(v0.x) | ((uint32_t)f32_to_bf16(v0.y) << 16);
        o.y = (uint32_t)f32_to_bf16(v0.z) | ((uint32_t)f32_to_bf16(v0.w) << 16);
        o.z = (uint32_t)f32_to_bf16(v1.x) | ((uint32_t)f32_to_bf16(v1.y) << 16);
        o.w = (uint32_t)f32_to_bf16(v1.z) | ((uint32_t)f32_to_bf16(v1.w) << 16);
        ((uint4*)Xb)[idx] = o;
    }
}

// ---------------------------------------------------------------------------
// Kernel 3: C[M,N] = A[M,K] * B[N,K]^T  (bf16 in, fp32 out).
// R16 = R13-exact (session optimum: GEMM 73.9 us, 40% MfmaUtil, 0 bank
// conflicts; total 227.8 us).  Structure: 128x128 tile, 256 thr (4 waves of
// 64x64), 4 thin phases/K-tile, T2 XOR-swizzle (pre-swizzled global source +
// swizzled ds_read), 2-buffer depth-1 prefetch (64 KiB -> 2 blocks/CU,
// grid 512), T1 XCD swizzle, setprio around MFMA clusters.
// Ledger of rejected alternatives (all measured): R10 fat-phase 77.5; R11
// coop-fusion 320 (occupancy); R12 B-from-global 152 (txn split); R14/R15
// 256^2+split-K 112/114 (atomic epilogue tax ~37 us, loop no better per-FLOP).
// ---------------------------------------------------------------------------
#define BM 128
#define BN 128
#define BK 64
#define NT (K_DIM / BK)                 // 64
#define BUF_ELEMS 16384                 // A 8192 + B 8192 elems = 32 KiB

#define MFMA16(d, a, b) d = __builtin_amdgcn_mfma_f32_16x16x32_bf16(a, b, d, 0, 0, 0)

__global__ __launch_bounds__(256, 2) void gemm_bt_kernel(
        const uint16_t* __restrict__ A,   // [2048][4096] bf16
        const uint16_t* __restrict__ B,   // [4096][4096] bf16 (row-major [N][K])
        float* __restrict__ C) {          // [2048][4096] fp32
    __shared__ uint16_t lds[2 * BUF_ELEMS];   // 64 KiB, 2 buffers

    const int tid  = threadIdx.x;
    const int wave = tid >> 6;           // 0..3
    const int lane = tid & 63;
    const int wm   = wave >> 1;          // 0..1  (64 rows)
    const int wn   = wave & 1;           // 0..1  (64 cols)

    // XCD-aware bijective block swizzle: 512 blocks, 8 XCDs (512 % 8 == 0)
    const int wgid = blockIdx.y * 32 + blockIdx.x;
    const int swz  = (wgid & 7) * 64 + (wgid >> 3);
    const int bm0  = (swz >> 5) * BM;    // 16 row-tiles
    const int bn0  = (swz & 31) * BN;    // 32 col-tiles

    // ---- staging: each wave stages 32 rows of A and 32 rows of B ----
    // per call: 8 rows x 64 k (1 KiB).  Source pre-swizzled (R9 involution):
    // LDS[r][q] holds global k-quad q^(r&7);  r within chunk = lane>>3.
    const int sr   = lane >> 3;                              // 0..7
    const int xcol = ((lane & 7) ^ sr) << 3;                 // swizzled k-elem
    const uint16_t* gA = A + (size_t)(bm0 + wave * 32 + sr) * K_DIM + xcol;
    const uint16_t* gB = B + (size_t)(bn0 + wave * 32 + sr) * K_DIM + xcol;
    const int ldsA = (wave * 32) * 64;                       // + c*512
    const int ldsB = 8192 + (wave * 32) * 64;                // + c*512

    // ---- LDS read addressing (R9-exact formulas) ----
    const int fr  = lane & 15;                  // fragment row
    const int ko  = (lane >> 4) << 3;           // fragment k offset in 32-slice
    const int sk0 = (ko)      ^ ((fr & 7) << 3);
    const int sk1 = (32 + ko) ^ ((fr & 7) << 3);
    const int raA = (wm * 64 + fr) * BK;                 // + i*1024
    const int raB = 8192 + (wn * 64 + fr) * BK;          // + j*1024

    floatx4 acc[4][4];
#pragma unroll
    for (int i = 0; i < 4; ++i)
#pragma unroll
        for (int j = 0; j < 4; ++j) acc[i][j] = {0.f, 0.f, 0.f, 0.f};

    // ---- prologue: stage tile0 -> buf0 (8 calls/wave), drain, barrier ----
#pragma unroll
    for (int c = 0; c < 4; ++c)
        load_lds16(gA + (size_t)(c * 8) * K_DIM, &lds[ldsA + c * 512]);
#pragma unroll
    for (int c = 0; c < 4; ++c)
        load_lds16(gB + (size_t)(c * 8) * K_DIM, &lds[ldsB + c * 512]);
    asm volatile("s_waitcnt vmcnt(0)" ::: "memory");
    __builtin_amdgcn_s_barrier();

    for (int t = 0; t < NT; ++t) {
        const int cb = (t & 1) * BUF_ELEMS;        // compute buffer
        const int sb = cb ^ BUF_ELEMS;             // stage buffer (tile t+1)
        const bool pf = (t + 1 < NT);
        const size_t kofs = (size_t)(t + 1) * BK;

        // ---- phase 0: read A0,A1,B0,B1 (8); stage A rows 0..23 of t+1 ----
        short8 a00 = *(const short8*)&lds[cb + raA + sk0];
        short8 a01 = *(const short8*)&lds[cb + raA + sk1];
        short8 a10 = *(const short8*)&lds[cb + raA + 1024 + sk0];
        short8 a11 = *(const short8*)&lds[cb + raA + 1024 + sk1];
        short8 b00 = *(const short8*)&lds[cb + raB + sk0];
        short8 b01 = *(const short8*)&lds[cb + raB + sk1];
        short8 b10 = *(const short8*)&lds[cb + raB + 1024 + sk0];
        short8 b11 = *(const short8*)&lds[cb + raB + 1024 + sk1];
        if (pf) {
            load_lds16(gA + kofs,                     &lds[sb + ldsA]);
            load_lds16(gA + kofs + (size_t)8 * K_DIM, &lds[sb + ldsA + 512]);
            load_lds16(gA + kofs + (size_t)16 * K_DIM,&lds[sb + ldsA + 1024]);
        }
        __builtin_amdgcn_s_barrier();
        asm volatile("s_waitcnt lgkmcnt(0)");
        __builtin_amdgcn_s_setprio(1);
        MFMA16(acc[0][0], a00, b00); MFMA16(acc[0][0], a01, b01);
        MFMA16(acc[0][1], a00, b10); MFMA16(acc[0][1], a01, b11);
        MFMA16(acc[1][0], a10, b00); MFMA16(acc[1][0], a11, b01);
        MFMA16(acc[1][1], a10, b10); MFMA16(acc[1][1], a11, b11);
        __builtin_amdgcn_s_setprio(0);
        __builtin_amdgcn_s_barrier();

        // ---- phase 1: read B2,B3 (4); stage A row 24.., B rows 0..15 ----
        short8 b20 = *(const short8*)&lds[cb + raB + 2048 + sk0];
        short8 b21 = *(const short8*)&lds[cb + raB + 2048 + sk1];
        short8 b30 = *(const short8*)&lds[cb + raB + 3072 + sk0];
        short8 b31 = *(const short8*)&lds[cb + raB + 3072 + sk1];
        if (pf) {
            load_lds16(gA + kofs + (size_t)24 * K_DIM,&lds[sb + ldsA + 1536]);
            load_lds16(gB + kofs,                     &lds[sb + ldsB]);
            load_lds16(gB + kofs + (size_t)8 * K_DIM, &lds[sb + ldsB + 512]);
        }
        __builtin_amdgcn_s_barrier();
        asm volatile("s_waitcnt lgkmcnt(0)");
        __builtin_amdgcn_s_setprio(1);
        MFMA16(acc[0][2], a00, b20); MFMA16(acc[0][2], a01, b21);
        MFMA16(acc[0][3], a00, b30); MFMA16(acc[0][3], a01, b31);
        MFMA16(acc[1][2], a10, b20); MFMA16(acc[1][2], a11, b21);
        MFMA16(acc[1][3], a10, b30); MFMA16(acc[1][3], a11, b31);
        __builtin_amdgcn_s_setprio(0);
        __builtin_amdgcn_s_barrier();

        // ---- phase 2: read A2,A3 (4); stage B rows 16..31 ----
        short8 a20 = *(const short8*)&lds[cb + raA + 2048 + sk0];
        short8 a21 = *(const short8*)&lds[cb + raA + 2048 + sk1];
        short8 a30 = *(const short8*)&lds[cb + raA + 3072 + sk0];
        short8 a31 = *(const short8*)&lds[cb + raA + 3072 + sk1];
        if (pf) {
            load_lds16(gB + kofs + (size_t)16 * K_DIM,&lds[sb + ldsB + 1024]);
            load_lds16(gB + kofs + (size_t)24 * K_DIM,&lds[sb + ldsB + 1536]);
        }
        __builtin_amdgcn_s_barrier();
        asm volatile("s_waitcnt lgkmcnt(0)");
        __builtin_amdgcn_s_setprio(1);
        MFMA16(acc[2][2], a20, b20); MFMA16(acc[2][2], a21, b21);
        MFMA16(acc[2][3], a20, b30); MFMA16(acc[2][3], a21, b31);
        MFMA16(acc[3][2], a30, b20); MFMA16(acc[3][2], a31, b21);
        MFMA16(acc[3][3], a30, b30); MFMA16(acc[3][3], a31, b31);
        __builtin_amdgcn_s_setprio(0);
        __builtin_amdgcn_s_barrier();

        // ---- phase 3: reuse regs; drain stage; tile barrier ----
        __builtin_amdgcn_s_setprio(1);
        MFMA16(acc[2][0], a20, b00); MFMA16(acc[2][0], a21, b01);
        MFMA16(acc[2][1], a20, b10); MFMA16(acc[2][1], a21, b11);
        MFMA16(acc[3][0], a30, b00); MFMA16(acc[3][0], a31, b01);
        MFMA16(acc[3][1], a30, b10); MFMA16(acc[3][1], a31, b11);
        __builtin_amdgcn_s_setprio(0);
        if (pf) {
            // tile t+1's 8 loads were issued across phases 0-2; sibling
            // block on this CU covers the residual drain stall.
            asm volatile("s_waitcnt vmcnt(0)" ::: "memory");
            __builtin_amdgcn_s_barrier();
        }
    }

    // epilogue: C/D layout col=lane&15, row=(lane>>4)*4+reg   [m89/m91]
    const int cn  = lane & 15;
    const int rb4 = (lane >> 4) * 4;
#pragma unroll
    for (int i = 0; i < 4; ++i)
#pragma unroll
        for (int j = 0; j < 4; ++j)
#pragma unroll
            for (int r = 0; r < 4; ++r) {
                const int row = bm0 + wm * 64 + i * 16 + rb4 + r;
                const int col = bn0 + wn * 64 + j * 16 + cn;
                C[(size_t)row * O_FEAT + col] = acc[i][j][r];
            }
}

// ---------------------------------------------------------------------------
extern "C" void kernel_launch(void* const* d_in, const int* in_sizes, int n_in,
                              void* d_out, int out_size, void* d_ws, size_t ws_size,
                              hipStream_t stream) {
    const float* x      = (const float*)d_in[0];
    const void*  packed = d_in[1];
    const float* scales = (const float*)d_in[2];
    const void*  vals   = d_in[3];
    const int*   rows   = (const int*)d_in[4];
    const int*   cols   = (const int*)d_in[5];
    const float* alpha  = (const float*)d_in[6];
    float*       out    = (float*)d_out;
    const int nnz = in_sizes[3];

    uint16_t* W  = (uint16_t*)d_ws;                                        // 32 MB
    uint16_t* Xb = (uint16_t*)((char*)d_ws + (size_t)O_FEAT * I_FEAT * 2); // 16 MB

    // 1) dequant int4 -> bf16 W
    dequant_kernel<<<8192, 256, 0, stream>>>(packed, scales, W);
    // 2) fused: scatter residual into W (blocks < 3328) + x -> bf16 (rest)
    scatter_xconv_kernel<<<SCATTER_BLOCKS + 4096, 256, 0, stream>>>(
        vals, rows, cols, alpha, x, W, Xb, nnz);
    // 3) GEMM: out = Xb (2048x4096) * W^T (4096x4096)
    gemm_bt_kernel<<<dim3(32, 16), 256, 0, stream>>>(Xb, W, out);
}